// Round 2
// baseline (115.458 us; speedup 1.0000x reference)
//
#include <hip/hip_runtime.h>
#include <hip/hip_bf16.h>

typedef __bf16 bf16_8 __attribute__((ext_vector_type(8)));
typedef float  f32x4  __attribute__((ext_vector_type(4)));

#define N_TOK 1024
#define C_IN  128
#define H1D   128
#define H2D   64
#define NBAT  2
#define AR_STRIDE 256
#define AR_BYTES (NBAT * N_TOK * AR_STRIDE * 4)

// ---------------------------------------------------------------------------
// Kernel 1: ar[m][h'] for m in [0,2048), h' in [0,256):
//   h' <  128 : a'[m][h'] = x[m] @ W1[0:128, h']  + b1[h']   (b1 folded in)
//   h' >= 128 : r [m][h'-128] = x[m] @ W1[128:256, h'-128]
// Block: 32 rows x 64 cols, 256 threads, K=128 staged in LDS.
// ---------------------------------------------------------------------------
__global__ __launch_bounds__(256) void prep_ar_kernel(
    const float* __restrict__ x, const float* __restrict__ W1,
    const float* __restrict__ b1, float* __restrict__ ar)
{
    const int m0 = blockIdx.x * 32;
    const int h0 = blockIdx.y * 64;
    __shared__ float xs[32 * 132];   // x tile, row-major, pad to 132
    __shared__ float wsh[128 * 64];  // W column tile [k][hh]
    const int t = threadIdx.x;

    // stage x tile: rows m0..m0+31, cols 0..127 (1024 float4)
    #pragma unroll
    for (int it = 0; it < 4; ++it) {
        int f = t + it * 256;
        int row = f >> 5, c4 = f & 31;
        f32x4 v = *(const f32x4*)(x + (m0 + row) * C_IN + c4 * 4);
        *(f32x4*)(xs + row * 132 + c4 * 4) = v;
    }
    // stage W tile: k 0..127 x 64 cols (2048 float4)
    const float* wsrc = (h0 < 128) ? (W1 + h0) : (W1 + 128 * H1D + (h0 - 128));
    #pragma unroll
    for (int it = 0; it < 8; ++it) {
        int f = t + it * 256;
        int k = f >> 4, c4 = f & 15;
        f32x4 v = *(const f32x4*)(wsrc + k * H1D + c4 * 4);
        *(f32x4*)(wsh + k * 64 + c4 * 4) = v;
    }
    __syncthreads();

    const int tx = t & 15, ty = t >> 4;
    const int r0 = ty * 2, r1 = r0 + 1;
    float acc0[4] = {0.f, 0.f, 0.f, 0.f};
    float acc1[4] = {0.f, 0.f, 0.f, 0.f};
    #pragma unroll 4
    for (int k = 0; k < 128; ++k) {
        f32x4 w = *(const f32x4*)(wsh + k * 64 + tx * 4);
        float x0 = xs[r0 * 132 + k];
        float x1 = xs[r1 * 132 + k];
        #pragma unroll
        for (int c = 0; c < 4; ++c) {
            acc0[c] = fmaf(x0, w[c], acc0[c]);
            acc1[c] = fmaf(x1, w[c], acc1[c]);
        }
    }
    f32x4 bv = {0.f, 0.f, 0.f, 0.f};
    if (h0 < 128) bv = *(const f32x4*)(b1 + h0 + tx * 4);
    f32x4 o0, o1;
    #pragma unroll
    for (int c = 0; c < 4; ++c) { o0[c] = acc0[c] + bv[c]; o1[c] = acc1[c] + bv[c]; }
    *(f32x4*)(ar + (m0 + r0) * AR_STRIDE + h0 + tx * 4) = o0;
    *(f32x4*)(ar + (m0 + r1) * AR_STRIDE + h0 + tx * 4) = o1;
}

// ---------------------------------------------------------------------------
// Kernel 2: W2 (fp32 [128][64]) -> bf16 B-fragments for mfma_f32_16x16x32_bf16
// frag layout: [f = ks*4+nt][lane][jj]  with  k = ks*32 + (lane>>4)*8 + jj,
//                                            g = nt*16 + (lane&15)
// ---------------------------------------------------------------------------
__global__ __launch_bounds__(256) void prep_frags_kernel(
    const float* __restrict__ W2, __bf16* __restrict__ frag)
{
    int e = blockIdx.x * 256 + threadIdx.x;  // 0..1023
    int f = e >> 6, l = e & 63;
    int ks = f >> 2, nt = f & 3;
    int kbase = ks * 32 + (l >> 4) * 8;
    int g = nt * 16 + (l & 15);
    bf16_8 v;
    #pragma unroll
    for (int jj = 0; jj < 8; ++jj)
        v[jj] = (__bf16)(W2[(kbase + jj) * H2D + g]);
    *(bf16_8*)(frag + e * 8) = v;   // 16B vector store
}

// ---------------------------------------------------------------------------
// Kernel 3: main pair-MLP. Block = 64 i-rows x 16 j-cols. 4 waves; wave w
// handles i = i0 + w*16 + mt. Per m-tile: A[m=jl][k] = relu(r[j0+jl][k] +
// a'[i][k]) (r in regs, a' LDS-broadcast), 4 ks x 4 nt MFMAs, epilogue
// relu(.+b2)·W3 + 16-lane butterfly, mask j>i, +b3.
// ---------------------------------------------------------------------------
__global__ __launch_bounds__(256) void pair_mlp_kernel(
    const float* __restrict__ ar, const __bf16* __restrict__ frag,
    const float* __restrict__ b2, const float* __restrict__ W3,
    const float* __restrict__ b3, float* __restrict__ out)
{
    const int j0 = blockIdx.x * 16;   // 64 j-tiles
    const int i0 = blockIdx.y * 64;   // 16 i-tiles
    const int b  = blockIdx.z;
    const int t  = threadIdx.x;
    float* outb = out + (size_t)b * N_TOK * N_TOK;

    if (j0 + 15 <= i0) {
        // fully masked tile: just write zeros (out is poisoned 0xAA)
        int row = t >> 2, q4 = t & 3;
        f32x4 z = {0.f, 0.f, 0.f, 0.f};
        *(f32x4*)(outb + (i0 + row) * N_TOK + j0 + q4 * 4) = z;
        return;
    }

    __shared__ float aLDS[64 * 128];  // a' rows i0..i0+63 (broadcast reads)
    __shared__ float rLDS[16 * 132];  // r rows j0..j0+15, pad +4
    const float* arb = ar + (size_t)b * N_TOK * AR_STRIDE;
    #pragma unroll
    for (int it = 0; it < 8; ++it) {
        int f = t + it * 256;
        int row = f >> 5, c4 = f & 31;
        *(f32x4*)(aLDS + row * 128 + c4 * 4) =
            *(const f32x4*)(arb + (i0 + row) * AR_STRIDE + c4 * 4);
    }
    #pragma unroll
    for (int it = 0; it < 2; ++it) {
        int f = t + it * 256;
        int row = f >> 5, c4 = f & 31;
        *(f32x4*)(rLDS + row * 132 + c4 * 4) =
            *(const f32x4*)(arb + (j0 + row) * AR_STRIDE + 128 + c4 * 4);
    }
    __syncthreads();

    const int lane = t & 63, w = t >> 6;
    const int q = lane >> 4, jl = lane & 15;

    // r regs: rr[ks][half] = r[j0+jl][ks*32 + q*8 + half*4 ..]
    f32x4 rr[4][2];
    #pragma unroll
    for (int ks = 0; ks < 4; ++ks) {
        rr[ks][0] = *(const f32x4*)(rLDS + jl * 132 + ks * 32 + q * 8);
        rr[ks][1] = *(const f32x4*)(rLDS + jl * 132 + ks * 32 + q * 8 + 4);
    }
    // W2 B-fragments in registers (64 VGPRs)
    bf16_8 bfr[4][4];
    #pragma unroll
    for (int ks = 0; ks < 4; ++ks)
        #pragma unroll
        for (int nt = 0; nt < 4; ++nt)
            bfr[ks][nt] = *((const bf16_8*)frag + (ks * 4 + nt) * 64 + lane);
    // epilogue constants for this lane's g-columns
    float b2v[4], w3v[4];
    #pragma unroll
    for (int nt = 0; nt < 4; ++nt) {
        b2v[nt] = b2[nt * 16 + jl];
        w3v[nt] = W3[nt * 16 + jl];
    }
    const float b3v = b3[0];

    for (int mt = 0; mt < 16; ++mt) {
        const int li = w * 16 + mt;
        const int i  = i0 + li;
        f32x4 acc[4];
        #pragma unroll
        for (int nt = 0; nt < 4; ++nt) {
            f32x4 z = {0.f, 0.f, 0.f, 0.f};
            acc[nt] = z;
        }
        #pragma unroll
        for (int ks = 0; ks < 4; ++ks) {
            f32x4 a0 = *(const f32x4*)(aLDS + li * 128 + ks * 32 + q * 8);
            f32x4 a1 = *(const f32x4*)(aLDS + li * 128 + ks * 32 + q * 8 + 4);
            bf16_8 af;
            #pragma unroll
            for (int e = 0; e < 4; ++e) {
                af[e]     = (__bf16)fmaxf(rr[ks][0][e] + a0[e], 0.f);
                af[4 + e] = (__bf16)fmaxf(rr[ks][1][e] + a1[e], 0.f);
            }
            #pragma unroll
            for (int nt = 0; nt < 4; ++nt)
                acc[nt] = __builtin_amdgcn_mfma_f32_16x16x32_bf16(
                    af, bfr[ks][nt], acc[nt], 0, 0, 0);
        }
        // epilogue: relu(acc + b2) · W3, then reduce over the 16 g-lanes
        float s0 = 0.f, s1 = 0.f, s2 = 0.f, s3 = 0.f;
        #pragma unroll
        for (int nt = 0; nt < 4; ++nt) {
            s0 = fmaf(fmaxf(acc[nt][0] + b2v[nt], 0.f), w3v[nt], s0);
            s1 = fmaf(fmaxf(acc[nt][1] + b2v[nt], 0.f), w3v[nt], s1);
            s2 = fmaf(fmaxf(acc[nt][2] + b2v[nt], 0.f), w3v[nt], s2);
            s3 = fmaf(fmaxf(acc[nt][3] + b2v[nt], 0.f), w3v[nt], s3);
        }
        #pragma unroll
        for (int off = 8; off >= 1; off >>= 1) {
            s0 += __shfl_xor(s0, off, 16);
            s1 += __shfl_xor(s1, off, 16);
            s2 += __shfl_xor(s2, off, 16);
            s3 += __shfl_xor(s3, off, 16);
        }
        // D row = q*4 + reg  ->  j = j0 + q*4 + reg. Lanes with jl<4 store reg=jl.
        if (jl < 4) {
            int j = j0 + q * 4 + jl;
            float val = (jl == 0) ? s0 : (jl == 1) ? s1 : (jl == 2) ? s2 : s3;
            float res = (j > i) ? (val + b3v) : 0.f;
            outb[i * N_TOK + j] = res;
        }
    }
}

extern "C" void kernel_launch(void* const* d_in, const int* in_sizes, int n_in,
                              void* d_out, int out_size, void* d_ws, size_t ws_size,
                              hipStream_t stream) {
    const float* x  = (const float*)d_in[0];
    const float* W1 = (const float*)d_in[1];
    const float* b1 = (const float*)d_in[2];
    const float* W2 = (const float*)d_in[3];
    const float* b2 = (const float*)d_in[4];
    const float* W3 = (const float*)d_in[5];
    const float* b3 = (const float*)d_in[6];
    float* out = (float*)d_out;

    float* ar = (float*)d_ws;                                    // 2 MB
    __bf16* frag = (__bf16*)((char*)d_ws + AR_BYTES);            // 16 KB

    prep_ar_kernel<<<dim3(64, 4), 256, 0, stream>>>(x, W1, b1, ar);
    prep_frags_kernel<<<dim3(4), 256, 0, stream>>>(W2, frag);
    pair_mlp_kernel<<<dim3(64, 16, 2), 256, 0, stream>>>(ar, frag, b2, W3, b3, out);
}